// Round 1
// baseline (565.386 us; speedup 1.0000x reference)
//
#include <hip/hip_runtime.h>
#include <stdint.h>

typedef __bf16 bf16x8 __attribute__((ext_vector_type(8)));
typedef float  f32x4  __attribute__((ext_vector_type(4)));
typedef unsigned short u16;
typedef u16 u16x8 __attribute__((ext_vector_type(8)));

__device__ __forceinline__ u16 f2bf(float f) {
  uint32_t u = __builtin_bit_cast(uint32_t, f);
  u += 0x7fffu + ((u >> 16) & 1u);
  return (u16)(u >> 16);
}

// ---------------- fp32 -> bf16 convert (8 elems/thread) ----------------
__global__ void cvt_f32_bf16(const float* __restrict__ in, u16* __restrict__ out, int n8) {
  int i = blockIdx.x * 256 + threadIdx.x;
  if (i >= n8) return;
  const float4* p = (const float4*)in + (size_t)i * 2;
  float4 a = p[0];
  float4 b = p[1];
  u16x8 r;
  r[0] = f2bf(a.x); r[1] = f2bf(a.y); r[2] = f2bf(a.z); r[3] = f2bf(a.w);
  r[4] = f2bf(b.x); r[5] = f2bf(b.y); r[6] = f2bf(b.z); r[7] = f2bf(b.w);
  ((u16x8*)out)[i] = r;
}

// ---------------- batched GEMM: C = A[M,K] * Bw[N,K]^T ----------------
// 128x128 tile, BK=32, 4 waves (2x2), wave tile 64x64 = 4x4 frags of 16x16x32.
struct GemmB3 {
  const u16* A[3];
  const u16* Bm[3];
  u16* C[3];
  float alpha[3];
};

template<bool F32OUT>
__global__ __launch_bounds__(256, 2)
void gemm_bt(GemmB3 args, float* __restrict__ Cf, const float* __restrict__ bias,
             int M, int N, int K)
{
  __shared__ u16 At[128 * 32];
  __shared__ u16 Bt[128 * 32];
  const int z = blockIdx.z;
  const u16* __restrict__ A  = args.A[z];
  const u16* __restrict__ Bw = args.Bm[z];
  const int bm = blockIdx.x * 128;
  const int bn = blockIdx.y * 128;
  const int tid = threadIdx.x;
  const int w  = tid >> 6;
  const int l  = tid & 63;
  const int lr = l & 15;
  const int lg = l >> 4;
  const int wr = (w >> 1) * 64;
  const int wc = (w & 1) * 64;

  f32x4 acc[4][4];
  #pragma unroll
  for (int m = 0; m < 4; ++m) {
    #pragma unroll
    for (int n = 0; n < 4; ++n) acc[m][n] = (f32x4){0.f, 0.f, 0.f, 0.f};
  }

  for (int k0 = 0; k0 < K; k0 += 32) {
    __syncthreads();
    // stage 8KB A + 8KB B; 16B granules, rotation swizzle pos=(g+(row>>1))&3
    #pragma unroll
    for (int i = 0; i < 2; ++i) {
      const int gidx = tid + i * 256;
      const int row  = gidx >> 2;   // 0..127
      const int g    = gidx & 3;    // k granule
      const int pos  = (g + (row >> 1)) & 3;
      bf16x8 va = *(const bf16x8*)(A  + (size_t)(bm + row) * K + k0 + g * 8);
      bf16x8 vb = *(const bf16x8*)(Bw + (size_t)(bn + row) * K + k0 + g * 8);
      *(bf16x8*)(At + row * 32 + pos * 8) = va;
      *(bf16x8*)(Bt + row * 32 + pos * 8) = vb;
    }
    __syncthreads();
    bf16x8 af[4], bfr[4];
    #pragma unroll
    for (int m = 0; m < 4; ++m) {
      const int row = wr + m * 16 + lr;
      const int pos = (lg + (row >> 1)) & 3;
      af[m] = *(const bf16x8*)(At + row * 32 + pos * 8);
    }
    #pragma unroll
    for (int n = 0; n < 4; ++n) {
      const int row = wc + n * 16 + lr;
      const int pos = (lg + (row >> 1)) & 3;
      bfr[n] = *(const bf16x8*)(Bt + row * 32 + pos * 8);
    }
    #pragma unroll
    for (int m = 0; m < 4; ++m) {
      #pragma unroll
      for (int n = 0; n < 4; ++n)
        acc[m][n] = __builtin_amdgcn_mfma_f32_16x16x32_bf16(af[m], bfr[n], acc[m][n], 0, 0, 0);
    }
  }

  if constexpr (F32OUT) {
    #pragma unroll
    for (int n = 0; n < 4; ++n) {
      const int col = bn + wc + n * 16 + lr;
      const float bv = bias[col];
      #pragma unroll
      for (int m = 0; m < 4; ++m) {
        const int rbase = bm + wr + m * 16 + lg * 4;
        #pragma unroll
        for (int j = 0; j < 4; ++j)
          Cf[(size_t)(rbase + j) * N + col] = acc[m][n][j] + bv;
      }
    }
  } else {
    u16* __restrict__ C = args.C[z];
    const float alpha = args.alpha[z];
    #pragma unroll
    for (int n = 0; n < 4; ++n) {
      const int col = bn + wc + n * 16 + lr;
      #pragma unroll
      for (int m = 0; m < 4; ++m) {
        const int rbase = bm + wr + m * 16 + lg * 4;
        #pragma unroll
        for (int j = 0; j < 4; ++j)
          C[(size_t)(rbase + j) * N + col] = f2bf(acc[m][n][j] * alpha);
      }
    }
  }
}

// ---------------- flash attention, d_qk = d_v = 128, causal ----------------
// grid (T/64, H, B); 256 threads = 4 waves; wave handles 16 q rows; SBLK=32.
__global__ __launch_bounds__(256, 2)
void mla_attn(const u16* __restrict__ Qu, const u16* __restrict__ Ku,
              const u16* __restrict__ Vu, u16* __restrict__ ctx, int T)
{
  __shared__ u16 Kt[32 * 128];   // [s][dh], XOR swizzle on 16B granule: pos = g ^ (s&7)
  __shared__ u16 Vt[128 * 32];   // [dh][s], rotation swizzle: pos = ((s>>3)+(dh>>1))&3
  __shared__ u16 Pb[4 * 16 * 32];// per-wave P tiles

  const int qt = blockIdx.x, h = blockIdx.y, b = blockIdx.z;
  const int qbase = qt * 64;
  const int tid = threadIdx.x;
  const int w  = tid >> 6;
  const int l  = tid & 63;
  const int lr = l & 15;
  const int lg = l >> 4;

  const size_t rs = 2048;
  const u16* Qp = Qu + (size_t)b * T * rs + (size_t)h * 128;
  const u16* Kp = Ku + (size_t)b * T * rs + (size_t)h * 128;
  const u16* Vp = Vu + (size_t)b * T * rs + (size_t)h * 128;

  // Q fragments held in registers: rows qbase + w*16 + lr, k = f*32 + lg*8
  bf16x8 qf[4];
  const int qrow = qbase + w * 16 + lr;
  #pragma unroll
  for (int f = 0; f < 4; ++f)
    qf[f] = *(const bf16x8*)(Qp + (size_t)qrow * rs + f * 32 + lg * 8);

  f32x4 acc[8];
  #pragma unroll
  for (int f = 0; f < 8; ++f) acc[f] = (f32x4){0.f, 0.f, 0.f, 0.f};
  float mrun[4], lrun[4];
  #pragma unroll
  for (int j = 0; j < 4; ++j) { mrun[j] = -INFINITY; lrun[j] = 0.f; }

  const int nT = qbase / 32 + 2;   // uniform trips per block; overshoot is masked
  u16* Pw = Pb + w * 512;

  for (int it = 0; it < nT; ++it) {
    const int s0 = it * 32;
    __syncthreads();
    // stage K tile [32 s][128 dh]
    #pragma unroll
    for (int i = 0; i < 2; ++i) {
      const int gidx = tid + i * 256;
      const int row = gidx >> 4;       // s 0..31
      const int g   = gidx & 15;       // dh granule
      bf16x8 v = *(const bf16x8*)(Kp + (size_t)(s0 + row) * rs + g * 8);
      *(bf16x8*)(Kt + row * 128 + (g ^ (row & 7)) * 8) = v;
    }
    // stage V transposed: Vt[dh][s]
    #pragma unroll
    for (int i = 0; i < 2; ++i) {
      const int gidx = tid + i * 256;
      const int srow = gidx >> 4;      // s 0..31
      const int g    = gidx & 15;      // dh block of 8
      u16x8 v = *(const u16x8*)(Vp + (size_t)(s0 + srow) * rs + g * 8);
      #pragma unroll
      for (int e = 0; e < 8; ++e) {
        const int dh = g * 8 + e;
        const int pos = ((srow >> 3) + (dh >> 1)) & 3;
        Vt[dh * 32 + pos * 8 + (srow & 7)] = v[e];
      }
    }
    __syncthreads();

    // QK^T: two 16-col tiles (c0: s0+0..15, c1: s0+16..31)
    f32x4 c0 = (f32x4){0.f,0.f,0.f,0.f}, c1 = (f32x4){0.f,0.f,0.f,0.f};
    #pragma unroll
    for (int f = 0; f < 4; ++f) {
      bf16x8 k0f = *(const bf16x8*)(Kt + lr * 128 + ((f * 4 + lg) ^ (lr & 7)) * 8);
      bf16x8 k1f = *(const bf16x8*)(Kt + (16 + lr) * 128 + ((f * 4 + lg) ^ (lr & 7)) * 8);
      c0 = __builtin_amdgcn_mfma_f32_16x16x32_bf16(qf[f], k0f, c0, 0, 0, 0);
      c1 = __builtin_amdgcn_mfma_f32_16x16x32_bf16(qf[f], k1f, c1, 0, 0, 0);
    }

    // causal mask + online softmax (rows live in 16-lane groups)
    const int qg = qbase + w * 16;
    float p0[4], p1[4], mx[4];
    #pragma unroll
    for (int j = 0; j < 4; ++j) {
      const int q = qg + lg * 4 + j;
      p0[j] = (s0 + lr      <= q) ? c0[j] : -INFINITY;
      p1[j] = (s0 + 16 + lr <= q) ? c1[j] : -INFINITY;
      mx[j] = fmaxf(p0[j], p1[j]);
    }
    #pragma unroll
    for (int j = 0; j < 4; ++j) {
      #pragma unroll
      for (int off = 1; off < 16; off <<= 1)
        mx[j] = fmaxf(mx[j], __shfl_xor(mx[j], off));
    }
    float scl[4];
    #pragma unroll
    for (int j = 0; j < 4; ++j) {
      const float mnew = fmaxf(mrun[j], mx[j]);
      scl[j] = __expf(mrun[j] - mnew);
      mrun[j] = mnew;
      p0[j] = __expf(p0[j] - mnew);
      p1[j] = __expf(p1[j] - mnew);
    }
    float rsum[4];
    #pragma unroll
    for (int j = 0; j < 4; ++j) {
      rsum[j] = p0[j] + p1[j];
      #pragma unroll
      for (int off = 1; off < 16; off <<= 1)
        rsum[j] += __shfl_xor(rsum[j], off);
      lrun[j] = lrun[j] * scl[j] + rsum[j];
    }
    #pragma unroll
    for (int f = 0; f < 8; ++f) {
      #pragma unroll
      for (int j = 0; j < 4; ++j) acc[f][j] *= scl[j];
    }
    // P -> wave-private LDS (C-layout write), read back in A-layout
    #pragma unroll
    for (int j = 0; j < 4; ++j) {
      const int prow = lg * 4 + j;
      Pw[prow * 32 + lr]      = f2bf(p0[j]);
      Pw[prow * 32 + 16 + lr] = f2bf(p1[j]);
    }
    asm volatile("s_waitcnt lgkmcnt(0)" ::: "memory");
    bf16x8 pf = *(const bf16x8*)(Pw + lr * 32 + lg * 8);
    #pragma unroll
    for (int f = 0; f < 8; ++f) {
      const int dh = f * 16 + lr;
      const int pos = (lg + (dh >> 1)) & 3;
      bf16x8 vf = *(const bf16x8*)(Vt + dh * 32 + pos * 8);
      acc[f] = __builtin_amdgcn_mfma_f32_16x16x32_bf16(pf, vf, acc[f], 0, 0, 0);
    }
  }

  // epilogue: ctx[b, q, h*128+dh] = acc / l
  #pragma unroll
  for (int f = 0; f < 8; ++f) {
    #pragma unroll
    for (int j = 0; j < 4; ++j) {
      const int q  = qbase + w * 16 + lg * 4 + j;
      const int dh = f * 16 + lr;
      ctx[((size_t)b * T + q) * rs + h * 128 + dh] = f2bf(acc[f][j] / lrun[j]);
    }
  }
}

// ---------------- launcher ----------------
extern "C" void kernel_launch(void* const* d_in, const int* in_sizes, int n_in,
                              void* d_out, int out_size, void* d_ws, size_t ws_size,
                              hipStream_t stream)
{
  (void)n_in; (void)out_size; (void)ws_size;
  const float* x   = (const float*)d_in[0];
  const float* qdw = (const float*)d_in[1];
  const float* kdw = (const float*)d_in[2];
  const float* vdw = (const float*)d_in[3];
  const float* quw = (const float*)d_in[4];
  const float* kuw = (const float*)d_in[5];
  const float* vuw = (const float*)d_in[6];
  const float* oww = (const float*)d_in[7];
  const float* ob  = (const float*)d_in[8];

  const int d = 2048, r = 512, T = 2048, H = 16;
  const int BT = in_sizes[0] / d;   // B*T = 4096
  const int Bb = BT / T;            // 2

  u16* p = (u16*)d_ws;
  auto take = [&](size_t n) { u16* q = p; p += n; return q; };
  u16* xb  = take((size_t)BT * d);
  u16* wqd = take((size_t)r * d);
  u16* wkd = take((size_t)r * d);
  u16* wvd = take((size_t)r * d);
  u16* wqu = take((size_t)d * r);
  u16* wku = take((size_t)d * r);
  u16* wvu = take((size_t)d * r);
  u16* wow = take((size_t)d * d);
  u16* Qd  = take((size_t)BT * r);
  u16* Kd  = take((size_t)BT * r);
  u16* Vd  = take((size_t)BT * r);
  u16* Qu  = take((size_t)BT * d);
  u16* Ku  = take((size_t)BT * d);
  u16* Vu  = take((size_t)BT * d);
  u16* ctx = take((size_t)BT * d);

  auto cvt = [&](const float* in, u16* out, size_t n) {
    int n8 = (int)(n / 8);
    cvt_f32_bf16<<<dim3((n8 + 255) / 256), dim3(256), 0, stream>>>(in, out, n8);
  };
  cvt(x,   xb,  (size_t)BT * d);
  cvt(qdw, wqd, (size_t)r * d);
  cvt(kdw, wkd, (size_t)r * d);
  cvt(vdw, wvd, (size_t)r * d);
  cvt(quw, wqu, (size_t)d * r);
  cvt(kuw, wku, (size_t)d * r);
  cvt(vuw, wvu, (size_t)d * r);
  cvt(oww, wow, (size_t)d * d);

  // down projections: Qd/Kd/Vd = x @ Wd^T   [BT,2048] -> [BT,512]
  GemmB3 g1;
  g1.A[0] = xb;  g1.A[1] = xb;  g1.A[2] = xb;
  g1.Bm[0] = wqd; g1.Bm[1] = wkd; g1.Bm[2] = wvd;
  g1.C[0] = Qd;  g1.C[1] = Kd;  g1.C[2] = Vd;
  g1.alpha[0] = 1.f; g1.alpha[1] = 1.f; g1.alpha[2] = 1.f;
  gemm_bt<false><<<dim3(BT / 128, r / 128, 3), dim3(256), 0, stream>>>(
      g1, nullptr, nullptr, BT, r, d);

  // up projections: Qu/Ku/Vu = {Qd,Kd,Vd} @ Wu^T  [BT,512] -> [BT,2048]
  // 1/sqrt(128) folded into Qu.
  GemmB3 g2;
  g2.A[0] = Qd;  g2.A[1] = Kd;  g2.A[2] = Vd;
  g2.Bm[0] = wqu; g2.Bm[1] = wku; g2.Bm[2] = wvu;
  g2.C[0] = Qu;  g2.C[1] = Ku;  g2.C[2] = Vu;
  g2.alpha[0] = 0.08838834764831845f; g2.alpha[1] = 1.f; g2.alpha[2] = 1.f;
  gemm_bt<false><<<dim3(BT / 128, d / 128, 3), dim3(256), 0, stream>>>(
      g2, nullptr, nullptr, BT, d, r);

  // flash attention
  mla_attn<<<dim3(T / 64, H, Bb), dim3(256), 0, stream>>>(Qu, Ku, Vu, ctx, T);

  // output projection: out = ctx @ out_w^T + out_b (fp32 out)
  GemmB3 g3;
  g3.A[0] = ctx; g3.A[1] = ctx; g3.A[2] = ctx;
  g3.Bm[0] = wow; g3.Bm[1] = wow; g3.Bm[2] = wow;
  g3.C[0] = nullptr; g3.C[1] = nullptr; g3.C[2] = nullptr;
  g3.alpha[0] = 1.f; g3.alpha[1] = 1.f; g3.alpha[2] = 1.f;
  gemm_bt<true><<<dim3(BT / 128, d / 128, 1), dim3(256), 0, stream>>>(
      g3, (float*)d_out, ob, BT, d, d);
}

// Round 2
// 249.384 us; speedup vs baseline: 2.2671x; 2.2671x over previous
//
#include <hip/hip_runtime.h>
#include <stdint.h>

typedef __bf16 bf16x8 __attribute__((ext_vector_type(8)));
typedef float  f32x4  __attribute__((ext_vector_type(4)));
typedef unsigned short u16;
typedef u16 u16x8 __attribute__((ext_vector_type(8)));

__device__ __forceinline__ u16 f2bf(float f) {
  uint32_t u = __builtin_bit_cast(uint32_t, f);
  u += 0x7fffu + ((u >> 16) & 1u);
  return (u16)(u >> 16);
}

// async global->LDS, 16B per lane; lds base must be wave-uniform (lane writes at +lane*16B)
__device__ __forceinline__ void async_cp16(const void* src, void* lds) {
  __builtin_amdgcn_global_load_lds(
      (const __attribute__((address_space(1))) uint32_t*)src,
      (__attribute__((address_space(3))) uint32_t*)lds, 16, 0, 0);
}

// ---------------- fp32 -> bf16 convert (8 elems/thread) ----------------
__global__ void cvt_f32_bf16(const float* __restrict__ in, u16* __restrict__ out, int n8) {
  int i = blockIdx.x * 256 + threadIdx.x;
  if (i >= n8) return;
  const float4* p = (const float4*)in + (size_t)i * 2;
  float4 a = p[0];
  float4 b = p[1];
  u16x8 r;
  r[0] = f2bf(a.x); r[1] = f2bf(a.y); r[2] = f2bf(a.z); r[3] = f2bf(a.w);
  r[4] = f2bf(b.x); r[5] = f2bf(b.y); r[6] = f2bf(b.z); r[7] = f2bf(b.w);
  ((u16x8*)out)[i] = r;
}

// ---------------- batched GEMM: C = A[M,K] * Bw[N,K]^T ----------------
// 128x128 tile, BK=32, 4 waves (2x2), wave tile 64x64 = 4x4 frags of 16x16x32.
// Staging via global_load_lds (linear LDS dest, pre-swizzled global source).
struct GemmB3 {
  const u16* A[3];
  const u16* Bm[3];
  u16* C[3];
  float alpha[3];
};

template<bool F32OUT>
__global__ __launch_bounds__(256, 2)
void gemm_bt(GemmB3 args, float* __restrict__ Cf, const float* __restrict__ bias,
             int M, int N, int K)
{
  __shared__ u16 At[128 * 32];
  __shared__ u16 Bt[128 * 32];
  const int z = blockIdx.z;
  const u16* __restrict__ A  = args.A[z];
  const u16* __restrict__ Bw = args.Bm[z];
  const int bm = blockIdx.x * 128;
  const int bn = blockIdx.y * 128;
  const int tid = threadIdx.x;
  const int w  = tid >> 6;
  const int l  = tid & 63;
  const int lr = l & 15;
  const int lg = l >> 4;
  const int wr = (w >> 1) * 64;
  const int wc = (w & 1) * 64;

  f32x4 acc[4][4];
  #pragma unroll
  for (int m = 0; m < 4; ++m) {
    #pragma unroll
    for (int n = 0; n < 4; ++n) acc[m][n] = (f32x4){0.f, 0.f, 0.f, 0.f};
  }

  for (int k0 = 0; k0 < K; k0 += 32) {
    __syncthreads();
    // rotation swizzle: stored pos p holds global granule (p - (row>>1))&3
    #pragma unroll
    for (int i = 0; i < 2; ++i) {
      const int gidx = i * 256 + tid;
      const int row  = gidx >> 2;   // 0..127
      const int g    = gidx & 3;    // stored pos
      const int gs   = (g - (row >> 1)) & 3;
      async_cp16(A  + (size_t)(bm + row) * K + k0 + gs * 8,
                 At + (size_t)(i * 256 + w * 64) * 8);
      async_cp16(Bw + (size_t)(bn + row) * K + k0 + gs * 8,
                 Bt + (size_t)(i * 256 + w * 64) * 8);
    }
    __syncthreads();
    bf16x8 af[4], bfr[4];
    #pragma unroll
    for (int m = 0; m < 4; ++m) {
      const int row = wr + m * 16 + lr;
      const int pos = (lg + (row >> 1)) & 3;
      af[m] = *(const bf16x8*)(At + row * 32 + pos * 8);
    }
    #pragma unroll
    for (int n = 0; n < 4; ++n) {
      const int row = wc + n * 16 + lr;
      const int pos = (lg + (row >> 1)) & 3;
      bfr[n] = *(const bf16x8*)(Bt + row * 32 + pos * 8);
    }
    #pragma unroll
    for (int m = 0; m < 4; ++m) {
      #pragma unroll
      for (int n = 0; n < 4; ++n)
        acc[m][n] = __builtin_amdgcn_mfma_f32_16x16x32_bf16(af[m], bfr[n], acc[m][n], 0, 0, 0);
    }
  }

  if constexpr (F32OUT) {
    #pragma unroll
    for (int n = 0; n < 4; ++n) {
      const int col = bn + wc + n * 16 + lr;
      const float bv = bias[col];
      #pragma unroll
      for (int m = 0; m < 4; ++m) {
        const int rbase = bm + wr + m * 16 + lg * 4;
        #pragma unroll
        for (int j = 0; j < 4; ++j)
          Cf[(size_t)(rbase + j) * N + col] = acc[m][n][j] + bv;
      }
    }
  } else {
    u16* __restrict__ C = args.C[z];
    const float alpha = args.alpha[z];
    #pragma unroll
    for (int n = 0; n < 4; ++n) {
      const int col = bn + wc + n * 16 + lr;
      #pragma unroll
      for (int m = 0; m < 4; ++m) {
        const int rbase = bm + wr + m * 16 + lg * 4;
        #pragma unroll
        for (int j = 0; j < 4; ++j)
          C[(size_t)(rbase + j) * N + col] = f2bf(acc[m][n][j] * alpha);
      }
    }
  }
}

// ---------------- flash attention, d=128, causal; V pre-transposed in global ----------------
// QBLK=64 (4 waves x 16 q rows), SBLK=64. grid = 1024 blocks: qt heavy-first, bh fast.
__global__ __launch_bounds__(256, 3)
void mla_attn(const u16* __restrict__ Qu, const u16* __restrict__ Ku,
              const u16* __restrict__ Vtg, u16* __restrict__ ctx)
{
  __shared__ u16 Kt[64 * 128];    // [s][dh], pos g holds dh-granule g^(s&7)
  __shared__ u16 Vt[128 * 64];    // [dh][s], pos g holds s-granule g^(dh&7)
  __shared__ u16 Pb[4 * 16 * 72]; // per-wave P [16 q][64 s], row stride 72

  const int bid = blockIdx.x;
  const int qt  = 31 - (bid >> 5);   // heavy tiles first (backfill-friendly)
  const int bh  = bid & 31;          // same bh -> same XCD (bid%8 invariant)
  const int b   = bh >> 4;
  const int h   = bh & 15;
  const int qbase = qt * 64;

  const int tid = threadIdx.x;
  const int w  = tid >> 6;
  const int l  = tid & 63;
  const int lr = l & 15;
  const int lg = l >> 4;

  const int T = 2048;
  const size_t rs = 2048;
  const u16* Qp = Qu + ((size_t)b * T) * rs + (size_t)h * 128;
  const u16* Kp = Ku + ((size_t)b * T) * rs + (size_t)h * 128;
  const u16* Vp = Vtg + (size_t)(h * 128) * 4096 + (size_t)b * T;  // + dh*4096 + s

  // Q frags in registers: row qbase + w*16 + lr, k = f*32 + lg*8
  bf16x8 qf[4];
  const int qrow = qbase + w * 16 + lr;
  #pragma unroll
  for (int f = 0; f < 4; ++f)
    qf[f] = *(const bf16x8*)(Qp + (size_t)qrow * rs + f * 32 + lg * 8);

  f32x4 acc[8];
  #pragma unroll
  for (int f = 0; f < 8; ++f) acc[f] = (f32x4){0.f, 0.f, 0.f, 0.f};
  float mrun[4], lrun[4];
  #pragma unroll
  for (int j = 0; j < 4; ++j) { mrun[j] = -INFINITY; lrun[j] = 0.f; }

  u16* Pw = Pb + w * (16 * 72);
  const int nT = qt + 1;

  for (int it = 0; it < nT; ++it) {
    const int s0 = it * 64;
    __syncthreads();
    // K tile: 64 rows x 16 granules; source pre-swizzled, LDS linear
    #pragma unroll
    for (int i = 0; i < 4; ++i) {
      const int gidx = i * 256 + tid;
      const int s = gidx >> 4, g = gidx & 15;
      async_cp16(Kp + (size_t)(s0 + s) * rs + ((g ^ (s & 7)) * 8),
                 Kt + (size_t)(i * 256 + w * 64) * 8);
    }
    // V tile: 128 dh rows x 8 granules along s
    #pragma unroll
    for (int i = 0; i < 4; ++i) {
      const int gidx = i * 256 + tid;
      const int dh = gidx >> 3, g = gidx & 7;
      async_cp16(Vp + (size_t)dh * 4096 + s0 + ((g ^ (dh & 7)) * 8),
                 Vt + (size_t)(i * 256 + w * 64) * 8);
    }
    __syncthreads();

    // QK^T: c[ct] covers s = s0 + ct*16 + lr
    f32x4 c[4];
    #pragma unroll
    for (int ct = 0; ct < 4; ++ct) c[ct] = (f32x4){0.f, 0.f, 0.f, 0.f};
    #pragma unroll
    for (int ct = 0; ct < 4; ++ct) {
      const int row = ct * 16 + lr;
      #pragma unroll
      for (int f = 0; f < 4; ++f) {
        bf16x8 kf = *(const bf16x8*)(Kt + row * 128 + (((f * 4 + lg) ^ (lr & 7)) * 8));
        c[ct] = __builtin_amdgcn_mfma_f32_16x16x32_bf16(qf[f], kf, c[ct], 0, 0, 0);
      }
    }

    // causal mask + online softmax (reduce over 16 lanes per lg-group)
    const int qg = qbase + w * 16 + lg * 4;
    float p[4][4], mx[4];
    #pragma unroll
    for (int j = 0; j < 4; ++j) mx[j] = -INFINITY;
    #pragma unroll
    for (int ct = 0; ct < 4; ++ct) {
      const int s = s0 + ct * 16 + lr;
      #pragma unroll
      for (int j = 0; j < 4; ++j) {
        p[ct][j] = (s <= qg + j) ? c[ct][j] : -INFINITY;
        mx[j] = fmaxf(mx[j], p[ct][j]);
      }
    }
    #pragma unroll
    for (int j = 0; j < 4; ++j) {
      #pragma unroll
      for (int off = 1; off < 16; off <<= 1)
        mx[j] = fmaxf(mx[j], __shfl_xor(mx[j], off));
    }
    float scl[4];
    #pragma unroll
    for (int j = 0; j < 4; ++j) {
      const float mnew = fmaxf(mrun[j], mx[j]);
      scl[j] = __expf(mrun[j] - mnew);
      mrun[j] = mnew;
      #pragma unroll
      for (int ct = 0; ct < 4; ++ct) p[ct][j] = __expf(p[ct][j] - mnew);
    }
    float rsum[4];
    #pragma unroll
    for (int j = 0; j < 4; ++j) {
      rsum[j] = (p[0][j] + p[1][j]) + (p[2][j] + p[3][j]);
      #pragma unroll
      for (int off = 1; off < 16; off <<= 1)
        rsum[j] += __shfl_xor(rsum[j], off);
      lrun[j] = lrun[j] * scl[j] + rsum[j];
    }
    #pragma unroll
    for (int f = 0; f < 8; ++f) {
      #pragma unroll
      for (int j = 0; j < 4; ++j) acc[f][j] *= scl[j];
    }

    // P -> wave-private LDS (C-layout write), read back as A-frags
    #pragma unroll
    for (int ct = 0; ct < 4; ++ct) {
      #pragma unroll
      for (int j = 0; j < 4; ++j)
        Pw[(lg * 4 + j) * 72 + ct * 16 + lr] = f2bf(p[ct][j]);
    }
    asm volatile("s_waitcnt lgkmcnt(0)" ::: "memory");
    bf16x8 pf0 = *(const bf16x8*)(Pw + lr * 72 + lg * 8);
    bf16x8 pf1 = *(const bf16x8*)(Pw + lr * 72 + 32 + lg * 8);

    // PV: acc[f] over dh tile f*16+lr; V frags contiguous along s
    #pragma unroll
    for (int f = 0; f < 8; ++f) {
      const int row = f * 16 + lr;
      bf16x8 v0 = *(const bf16x8*)(Vt + row * 64 + ((lg ^ (lr & 7)) * 8));
      bf16x8 v1 = *(const bf16x8*)(Vt + row * 64 + (((4 + lg) ^ (lr & 7)) * 8));
      acc[f] = __builtin_amdgcn_mfma_f32_16x16x32_bf16(pf0, v0, acc[f], 0, 0, 0);
      acc[f] = __builtin_amdgcn_mfma_f32_16x16x32_bf16(pf1, v1, acc[f], 0, 0, 0);
    }
  }

  // epilogue
  #pragma unroll
  for (int f = 0; f < 8; ++f) {
    #pragma unroll
    for (int j = 0; j < 4; ++j) {
      const int q = qbase + w * 16 + lg * 4 + j;
      ctx[((size_t)b * T + q) * rs + h * 128 + f * 16 + lr] = f2bf(acc[f][j] / lrun[j]);
    }
  }
}

// ---------------- launcher ----------------
extern "C" void kernel_launch(void* const* d_in, const int* in_sizes, int n_in,
                              void* d_out, int out_size, void* d_ws, size_t ws_size,
                              hipStream_t stream)
{
  (void)n_in; (void)out_size; (void)ws_size;
  const float* x   = (const float*)d_in[0];
  const float* qdw = (const float*)d_in[1];
  const float* kdw = (const float*)d_in[2];
  const float* vdw = (const float*)d_in[3];
  const float* quw = (const float*)d_in[4];
  const float* kuw = (const float*)d_in[5];
  const float* vuw = (const float*)d_in[6];
  const float* oww = (const float*)d_in[7];
  const float* ob  = (const float*)d_in[8];

  const int d = 2048, r = 512, T = 2048, H = 16;
  const int BT = in_sizes[0] / d;   // B*T = 4096
  (void)T; (void)H;

  u16* p = (u16*)d_ws;
  auto take = [&](size_t n) { u16* q = p; p += n; return q; };
  u16* xb  = take((size_t)BT * d);
  u16* wqd = take((size_t)r * d);
  u16* wkd = take((size_t)r * d);
  u16* wvd = take((size_t)r * d);
  u16* wqu = take((size_t)d * r);
  u16* wku = take((size_t)d * r);
  u16* wvu = take((size_t)d * r);
  u16* wow = take((size_t)d * d);
  u16* Qd  = take((size_t)BT * r);
  u16* Kd  = take((size_t)BT * r);
  u16* Vd  = take((size_t)BT * r);
  u16* Qu  = take((size_t)BT * d);
  u16* Ku  = take((size_t)BT * d);
  u16* Vtg = take((size_t)BT * d);   // transposed: [d][BT]
  u16* ctx = take((size_t)BT * d);

  auto cvt = [&](const float* in, u16* out, size_t n) {
    int n8 = (int)(n / 8);
    cvt_f32_bf16<<<dim3((n8 + 255) / 256), dim3(256), 0, stream>>>(in, out, n8);
  };
  cvt(x,   xb,  (size_t)BT * d);
  cvt(qdw, wqd, (size_t)r * d);
  cvt(kdw, wkd, (size_t)r * d);
  cvt(vdw, wvd, (size_t)r * d);
  cvt(quw, wqu, (size_t)d * r);
  cvt(kuw, wku, (size_t)d * r);
  cvt(vuw, wvu, (size_t)d * r);
  cvt(oww, wow, (size_t)d * d);

  // down projections: Qd/Kd/Vd = x @ Wd^T   [BT,2048] -> [BT,512]
  GemmB3 g1;
  g1.A[0] = xb;  g1.A[1] = xb;  g1.A[2] = xb;
  g1.Bm[0] = wqd; g1.Bm[1] = wkd; g1.Bm[2] = wvd;
  g1.C[0] = Qd;  g1.C[1] = Kd;  g1.C[2] = Vd;
  g1.alpha[0] = 1.f; g1.alpha[1] = 1.f; g1.alpha[2] = 1.f;
  gemm_bt<false><<<dim3(BT / 128, r / 128, 3), dim3(256), 0, stream>>>(
      g1, nullptr, nullptr, BT, r, d);

  // Q/K up projections: [BT,512] -> [BT,2048]; 1/sqrt(128) folded into Qu
  GemmB3 g2;
  g2.A[0] = Qd;  g2.A[1] = Kd;  g2.A[2] = Kd;
  g2.Bm[0] = wqu; g2.Bm[1] = wku; g2.Bm[2] = wku;
  g2.C[0] = Qu;  g2.C[1] = Ku;  g2.C[2] = Ku;
  g2.alpha[0] = 0.08838834764831845f; g2.alpha[1] = 1.f; g2.alpha[2] = 1.f;
  gemm_bt<false><<<dim3(BT / 128, d / 128, 2), dim3(256), 0, stream>>>(
      g2, nullptr, nullptr, BT, d, r);

  // V up projection, TRANSPOSED output: Vtg[dh][bt] = vuw[dh,:] . Vd[bt,:]
  GemmB3 g2v;
  g2v.A[0] = wvu; g2v.A[1] = wvu; g2v.A[2] = wvu;
  g2v.Bm[0] = Vd; g2v.Bm[1] = Vd; g2v.Bm[2] = Vd;
  g2v.C[0] = Vtg; g2v.C[1] = Vtg; g2v.C[2] = Vtg;
  g2v.alpha[0] = 1.f; g2v.alpha[1] = 1.f; g2v.alpha[2] = 1.f;
  gemm_bt<false><<<dim3(d / 128, BT / 128, 1), dim3(256), 0, stream>>>(
      g2v, nullptr, nullptr, d, BT, r);

  // flash attention (V transposed in global)
  mla_attn<<<dim3(1024), dim3(256), 0, stream>>>(Qu, Ku, Vtg, ctx);

  // output projection: out = ctx @ out_w^T + out_b (fp32 out)
  GemmB3 g3;
  g3.A[0] = ctx; g3.A[1] = ctx; g3.A[2] = ctx;
  g3.Bm[0] = wow; g3.Bm[1] = wow; g3.Bm[2] = wow;
  g3.C[0] = nullptr; g3.C[1] = nullptr; g3.C[2] = nullptr;
  g3.alpha[0] = 1.f; g3.alpha[1] = 1.f; g3.alpha[2] = 1.f;
  gemm_bt<true><<<dim3(BT / 128, d / 128, 1), dim3(256), 0, stream>>>(
      g3, (float*)d_out, ob, BT, d, d);
}

// Round 3
// 242.481 us; speedup vs baseline: 2.3317x; 1.0285x over previous
//
#include <hip/hip_runtime.h>
#include <stdint.h>

typedef __bf16 bf16x8 __attribute__((ext_vector_type(8)));
typedef float  f32x4  __attribute__((ext_vector_type(4)));
typedef unsigned short u16;
typedef u16 u16x8 __attribute__((ext_vector_type(8)));

__device__ __forceinline__ u16 f2bf(float f) {
  uint32_t u = __builtin_bit_cast(uint32_t, f);
  u += 0x7fffu + ((u >> 16) & 1u);
  return (u16)(u >> 16);
}

// async global->LDS, 16B per lane; lds base is wave-uniform (lane writes at +lane*16B)
__device__ __forceinline__ void async_cp16(const void* src, void* lds) {
  __builtin_amdgcn_global_load_lds(
      (const __attribute__((address_space(1))) uint32_t*)src,
      (__attribute__((address_space(3))) uint32_t*)lds, 16, 0, 0);
}

// ---------------- fused fp32 -> bf16 converts (one launch for all tensors) ----
struct CvtArgs {
  const float* in[8];
  u16* out[8];
  int n8[8];
  int nblk[8];
};
__global__ void cvt_multi(CvtArgs a) {
  int bx = blockIdx.x;
  int t = 0;
  while (t < 7 && bx >= a.nblk[t]) { bx -= a.nblk[t]; ++t; }
  const int i = bx * 256 + threadIdx.x;
  if (i >= a.n8[t]) return;
  const float4* p = (const float4*)a.in[t] + (size_t)i * 2;
  float4 va = p[0], vb = p[1];
  u16x8 r;
  r[0] = f2bf(va.x); r[1] = f2bf(va.y); r[2] = f2bf(va.z); r[3] = f2bf(va.w);
  r[4] = f2bf(vb.x); r[5] = f2bf(vb.y); r[6] = f2bf(vb.z); r[7] = f2bf(vb.w);
  ((u16x8*)a.out[t])[i] = r;
}

// ---------------- batched GEMM: C = A[M,K] * Bw[N,K]^T ----------------
// 128x128 tile, BK=32, 4 waves (2x2), wave tile 64x64 = 4x4 frags of 16x16x32.
struct GemmB3 {
  const u16* A[3];
  const u16* Bm[3];
  u16* C[3];
  float alpha[3];
};

template<bool F32OUT>
__global__ __launch_bounds__(256, 2)
void gemm_bt(GemmB3 args, float* __restrict__ Cf, const float* __restrict__ bias,
             int M, int N, int K)
{
  __shared__ u16 At[128 * 32];
  __shared__ u16 Bt[128 * 32];
  const int z = blockIdx.z;
  const u16* __restrict__ A  = args.A[z];
  const u16* __restrict__ Bw = args.Bm[z];
  const int bm = blockIdx.x * 128;
  const int bn = blockIdx.y * 128;
  const int tid = threadIdx.x;
  const int w  = tid >> 6;
  const int l  = tid & 63;
  const int lr = l & 15;
  const int lg = l >> 4;
  const int wr = (w >> 1) * 64;
  const int wc = (w & 1) * 64;

  f32x4 acc[4][4];
  #pragma unroll
  for (int m = 0; m < 4; ++m) {
    #pragma unroll
    for (int n = 0; n < 4; ++n) acc[m][n] = (f32x4){0.f, 0.f, 0.f, 0.f};
  }

  for (int k0 = 0; k0 < K; k0 += 32) {
    __syncthreads();
    #pragma unroll
    for (int i = 0; i < 2; ++i) {
      const int gidx = i * 256 + tid;
      const int row  = gidx >> 2;
      const int g    = gidx & 3;
      const int gs   = (g - (row >> 1)) & 3;
      async_cp16(A  + (size_t)(bm + row) * K + k0 + gs * 8,
                 At + (size_t)(i * 256 + w * 64) * 8);
      async_cp16(Bw + (size_t)(bn + row) * K + k0 + gs * 8,
                 Bt + (size_t)(i * 256 + w * 64) * 8);
    }
    __syncthreads();
    bf16x8 af[4], bfr[4];
    #pragma unroll
    for (int m = 0; m < 4; ++m) {
      const int row = wr + m * 16 + lr;
      const int pos = (lg + (row >> 1)) & 3;
      af[m] = *(const bf16x8*)(At + row * 32 + pos * 8);
    }
    #pragma unroll
    for (int n = 0; n < 4; ++n) {
      const int row = wc + n * 16 + lr;
      const int pos = (lg + (row >> 1)) & 3;
      bfr[n] = *(const bf16x8*)(Bt + row * 32 + pos * 8);
    }
    #pragma unroll
    for (int m = 0; m < 4; ++m) {
      #pragma unroll
      for (int n = 0; n < 4; ++n)
        acc[m][n] = __builtin_amdgcn_mfma_f32_16x16x32_bf16(af[m], bfr[n], acc[m][n], 0, 0, 0);
    }
  }

  if constexpr (F32OUT) {
    #pragma unroll
    for (int n = 0; n < 4; ++n) {
      const int col = bn + wc + n * 16 + lr;
      const float bv = bias[col];
      #pragma unroll
      for (int m = 0; m < 4; ++m) {
        const int rbase = bm + wr + m * 16 + lg * 4;
        #pragma unroll
        for (int j = 0; j < 4; ++j)
          Cf[(size_t)(rbase + j) * N + col] = acc[m][n][j] + bv;
      }
    }
  } else {
    u16* __restrict__ C = args.C[z];
    const float alpha = args.alpha[z];
    #pragma unroll
    for (int n = 0; n < 4; ++n) {
      const int col = bn + wc + n * 16 + lr;
      #pragma unroll
      for (int m = 0; m < 4; ++m) {
        const int rbase = bm + wr + m * 16 + lg * 4;
        #pragma unroll
        for (int j = 0; j < 4; ++j)
          C[(size_t)(rbase + j) * N + col] = f2bf(acc[m][n][j] * alpha);
      }
    }
  }
}

// ---------------- flash attention, d=128, causal; V pre-transposed in global --
// QBLK=64 (4 waves x 16 q rows), SBLK=64, double-buffered K/V staging.
// Softmax in exp2 domain (log2e folded into Q); denominator via ones-MFMA;
// defer-max rescale (THR=8).
__global__ __launch_bounds__(256, 2)
void mla_attn(const u16* __restrict__ Qu, const u16* __restrict__ Ku,
              const u16* __restrict__ Vtg, u16* __restrict__ ctx)
{
  __shared__ u16 Ktb[2][64 * 128];   // [s][dh], pos g holds dh-granule g^(s&7)
  __shared__ u16 Vtb[2][128 * 64];   // [dh][s], pos g holds s-granule g^(dh&7)
  __shared__ u16 Pb[4][16 * 72];     // per-wave P [16 q][64 s], row stride 72

  const int bid = blockIdx.x;
  const int kk  = bid >> 5;
  const int qt  = (kk & 1) ? (kk >> 1) : (31 - (kk >> 1));  // heavy/light interleave
  const int bh  = bid & 31;
  const int b = bh >> 4, h = bh & 15;
  const int qbase = qt * 64;
  const int tid = threadIdx.x;
  const int w = tid >> 6, l = tid & 63, lr = l & 15, lg = l >> 4;
  const int T = 2048;
  const size_t rs = 2048;
  const u16* Qp = Qu + ((size_t)b * T) * rs + (size_t)h * 128;
  const u16* Kp = Ku + ((size_t)b * T) * rs + (size_t)h * 128;
  const u16* Vp = Vtg + (size_t)(h * 128) * 4096 + (size_t)b * T;  // + dh*4096 + s

  bf16x8 qf[4];
  const int qrow = qbase + w * 16 + lr;
  #pragma unroll
  for (int f = 0; f < 4; ++f)
    qf[f] = *(const bf16x8*)(Qp + (size_t)qrow * rs + f * 32 + lg * 8);

  f32x4 acc[8];
  #pragma unroll
  for (int f = 0; f < 8; ++f) acc[f] = (f32x4){0.f, 0.f, 0.f, 0.f};
  f32x4 lacc = (f32x4){0.f, 0.f, 0.f, 0.f};
  float mrun[4];
  #pragma unroll
  for (int j = 0; j < 4; ++j) mrun[j] = -INFINITY;

  u16x8 onebits;
  #pragma unroll
  for (int e = 0; e < 8; ++e) onebits[e] = 0x3F80;  // bf16 1.0
  const bf16x8 ones = __builtin_bit_cast(bf16x8, onebits);

  u16* Pw = Pb[w];
  const int nT = qt + 1;

  auto stage = [&](int buf, int it) {
    const int s0 = it * 64;
    #pragma unroll
    for (int i = 0; i < 4; ++i) {
      const int gidx = i * 256 + tid;
      const int s = gidx >> 4, g = gidx & 15;
      async_cp16(Kp + (size_t)(s0 + s) * rs + ((g ^ (s & 7)) * 8),
                 &Ktb[buf][(i * 256 + w * 64) * 8]);
    }
    #pragma unroll
    for (int i = 0; i < 4; ++i) {
      const int gidx = i * 256 + tid;
      const int dh = gidx >> 3, g = gidx & 7;
      async_cp16(Vp + (size_t)dh * 4096 + s0 + ((g ^ (dh & 7)) * 8),
                 &Vtb[buf][(i * 256 + w * 64) * 8]);
    }
  };

  stage(0, 0);
  int cur = 0;

  for (int it = 0; it < nT; ++it) {
    __syncthreads();                       // drains prefetch of tile `it`
    if (it + 1 < nT) stage(cur ^ 1, it + 1);  // prefetch next under compute
    const u16* Kt = Ktb[cur];
    const u16* Vt = Vtb[cur];

    // QK^T: c[ct] covers s = it*64 + ct*16 + lr
    f32x4 c[4];
    #pragma unroll
    for (int ct = 0; ct < 4; ++ct) c[ct] = (f32x4){0.f, 0.f, 0.f, 0.f};
    __builtin_amdgcn_s_setprio(1);
    #pragma unroll
    for (int ct = 0; ct < 4; ++ct) {
      const int row = ct * 16 + lr;
      #pragma unroll
      for (int f = 0; f < 4; ++f) {
        bf16x8 kf = *(const bf16x8*)(Kt + row * 128 + (((f * 4 + lg) ^ (lr & 7)) * 8));
        c[ct] = __builtin_amdgcn_mfma_f32_16x16x32_bf16(qf[f], kf, c[ct], 0, 0, 0);
      }
    }
    __builtin_amdgcn_s_setprio(0);

    float p[4][4], mx[4];
    if (it == nT - 1) {   // only the diagonal tile needs the causal mask
      const int qg = qbase + w * 16 + lg * 4;
      #pragma unroll
      for (int j = 0; j < 4; ++j) mx[j] = -INFINITY;
      #pragma unroll
      for (int ct = 0; ct < 4; ++ct) {
        const int s = it * 64 + ct * 16 + lr;
        #pragma unroll
        for (int j = 0; j < 4; ++j) {
          p[ct][j] = (s <= qg + j) ? c[ct][j] : -INFINITY;
          mx[j] = fmaxf(mx[j], p[ct][j]);
        }
      }
    } else {
      #pragma unroll
      for (int ct = 0; ct < 4; ++ct)
        #pragma unroll
        for (int j = 0; j < 4; ++j) p[ct][j] = c[ct][j];
      #pragma unroll
      for (int j = 0; j < 4; ++j)
        mx[j] = fmaxf(fmaxf(p[0][j], p[1][j]), fmaxf(p[2][j], p[3][j]));
    }
    #pragma unroll
    for (int j = 0; j < 4; ++j) {
      #pragma unroll
      for (int off = 1; off < 16; off <<= 1)
        mx[j] = fmaxf(mx[j], __shfl_xor(mx[j], off));
    }
    // defer-max: rescale only when the running max grew by more than 8 (log2 units)
    int over = 0;
    #pragma unroll
    for (int j = 0; j < 4; ++j) over |= (mx[j] > mrun[j] + 8.f) ? 1 : 0;
    if (__any(over)) {
      #pragma unroll
      for (int j = 0; j < 4; ++j) {
        const float mnew = fmaxf(mrun[j], mx[j]);
        const float scl = exp2f(mrun[j] - mnew);
        mrun[j] = mnew;
        lacc[j] *= scl;
        #pragma unroll
        for (int f = 0; f < 8; ++f) acc[f][j] *= scl;
      }
    }
    #pragma unroll
    for (int ct = 0; ct < 4; ++ct)
      #pragma unroll
      for (int j = 0; j < 4; ++j) p[ct][j] = exp2f(p[ct][j] - mrun[j]);

    // P -> wave-private LDS (C-layout write), read back as A-frags
    #pragma unroll
    for (int ct = 0; ct < 4; ++ct)
      #pragma unroll
      for (int j = 0; j < 4; ++j)
        Pw[(lg * 4 + j) * 72 + ct * 16 + lr] = f2bf(p[ct][j]);
    asm volatile("s_waitcnt lgkmcnt(0)" ::: "memory");
    __builtin_amdgcn_sched_barrier(0);
    bf16x8 pf0 = *(const bf16x8*)(Pw + lr * 72 + lg * 8);
    bf16x8 pf1 = *(const bf16x8*)(Pw + lr * 72 + 32 + lg * 8);

    __builtin_amdgcn_s_setprio(1);
    // denominator via ones-column MFMA (replaces 32 shfl+add)
    lacc = __builtin_amdgcn_mfma_f32_16x16x32_bf16(pf0, ones, lacc, 0, 0, 0);
    lacc = __builtin_amdgcn_mfma_f32_16x16x32_bf16(pf1, ones, lacc, 0, 0, 0);
    #pragma unroll
    for (int f = 0; f < 8; ++f) {
      const int row = f * 16 + lr;
      bf16x8 v0 = *(const bf16x8*)(Vt + row * 64 + ((lg ^ (lr & 7)) * 8));
      bf16x8 v1 = *(const bf16x8*)(Vt + row * 64 + (((4 + lg) ^ (lr & 7)) * 8));
      acc[f] = __builtin_amdgcn_mfma_f32_16x16x32_bf16(pf0, v0, acc[f], 0, 0, 0);
      acc[f] = __builtin_amdgcn_mfma_f32_16x16x32_bf16(pf1, v1, acc[f], 0, 0, 0);
    }
    __builtin_amdgcn_s_setprio(0);
    cur ^= 1;
  }

  // epilogue: stage normalized O in LDS, store coalesced 256B rows
  __syncthreads();
  u16* Ot = &Ktb[0][0];     // 64x128 u16 = 16KB, reuse K buffer 0
  float inv[4];
  #pragma unroll
  for (int j = 0; j < 4; ++j) inv[j] = 1.f / lacc[j];
  #pragma unroll
  for (int f = 0; f < 8; ++f) {
    #pragma unroll
    for (int j = 0; j < 4; ++j) {
      const int q = w * 16 + lg * 4 + j;
      const int dh = f * 16 + lr;
      Ot[q * 128 + (dh ^ ((q & 7) << 3))] = f2bf(acc[f][j] * inv[j]);
    }
  }
  __syncthreads();
  const size_t obase = ((size_t)b * T + qbase) * rs + (size_t)h * 128;
  #pragma unroll
  for (int i = 0; i < 4; ++i) {
    const int gi = i * 256 + tid;
    const int q = gi >> 4, g = gi & 15;
    bf16x8 v = *(const bf16x8*)(Ot + q * 128 + ((g ^ (q & 7)) * 8));
    *(bf16x8*)(ctx + obase + (size_t)q * rs + g * 8) = v;
  }
}

// ---------------- launcher ----------------
extern "C" void kernel_launch(void* const* d_in, const int* in_sizes, int n_in,
                              void* d_out, int out_size, void* d_ws, size_t ws_size,
                              hipStream_t stream)
{
  (void)n_in; (void)out_size; (void)ws_size;
  const float* x   = (const float*)d_in[0];
  const float* qdw = (const float*)d_in[1];
  const float* kdw = (const float*)d_in[2];
  const float* vdw = (const float*)d_in[3];
  const float* quw = (const float*)d_in[4];
  const float* kuw = (const float*)d_in[5];
  const float* vuw = (const float*)d_in[6];
  const float* oww = (const float*)d_in[7];
  const float* ob  = (const float*)d_in[8];

  const int d = 2048, r = 512;
  const int BT = in_sizes[0] / d;   // B*T = 4096

  u16* p = (u16*)d_ws;
  auto take = [&](size_t n) { u16* q = p; p += n; return q; };
  u16* xb  = take((size_t)BT * d);
  u16* wqd = take((size_t)r * d);
  u16* wkd = take((size_t)r * d);
  u16* wvd = take((size_t)r * d);
  u16* wqu = take((size_t)d * r);
  u16* wku = take((size_t)d * r);
  u16* wvu = take((size_t)d * r);
  u16* wow = take((size_t)d * d);
  u16* Qd  = take((size_t)BT * r);
  u16* Kd  = take((size_t)BT * r);
  u16* Vd  = take((size_t)BT * r);
  u16* Qu  = take((size_t)BT * d);
  u16* Ku  = take((size_t)BT * d);
  u16* Vtg = take((size_t)BT * d);   // transposed: [d][BT]
  u16* ctx = take((size_t)BT * d);

  // one fused convert launch for all 8 tensors
  CvtArgs ca;
  const float* ins[8] = {x, oww, qdw, kdw, vdw, quw, kuw, vuw};
  u16* outs[8]        = {xb, wow, wqd, wkd, wvd, wqu, wku, wvu};
  const size_t ns[8]  = {(size_t)BT * d, (size_t)d * d,
                         (size_t)r * d, (size_t)r * d, (size_t)r * d,
                         (size_t)d * r, (size_t)d * r, (size_t)d * r};
  int total_blk = 0;
  for (int t = 0; t < 8; ++t) {
    ca.in[t] = ins[t]; ca.out[t] = outs[t];
    ca.n8[t] = (int)(ns[t] / 8);
    ca.nblk[t] = (ca.n8[t] + 255) / 256;
    total_blk += ca.nblk[t];
  }
  cvt_multi<<<dim3(total_blk), dim3(256), 0, stream>>>(ca);

  // down projections: Qd/Kd/Vd = x @ Wd^T   [BT,2048] -> [BT,512]
  GemmB3 g1;
  g1.A[0] = xb;  g1.A[1] = xb;  g1.A[2] = xb;
  g1.Bm[0] = wqd; g1.Bm[1] = wkd; g1.Bm[2] = wvd;
  g1.C[0] = Qd;  g1.C[1] = Kd;  g1.C[2] = Vd;
  g1.alpha[0] = 1.f; g1.alpha[1] = 1.f; g1.alpha[2] = 1.f;
  gemm_bt<false><<<dim3(BT / 128, r / 128, 3), dim3(256), 0, stream>>>(
      g1, nullptr, nullptr, BT, r, d);

  // Q/K up projections; log2(e)/sqrt(128) folded into Qu (exp2-domain softmax)
  GemmB3 g2;
  g2.A[0] = Qd;  g2.A[1] = Kd;  g2.A[2] = Kd;
  g2.Bm[0] = wqu; g2.Bm[1] = wku; g2.Bm[2] = wku;
  g2.C[0] = Qu;  g2.C[1] = Ku;  g2.C[2] = Ku;
  g2.alpha[0] = 0.12751743f; g2.alpha[1] = 1.f; g2.alpha[2] = 1.f;
  gemm_bt<false><<<dim3(BT / 128, d / 128, 2), dim3(256), 0, stream>>>(
      g2, nullptr, nullptr, BT, d, r);

  // V up projection, TRANSPOSED output: Vtg[dh][bt] = vuw[dh,:] . Vd[bt,:]
  GemmB3 g2v;
  g2v.A[0] = wvu; g2v.A[1] = wvu; g2v.A[2] = wvu;
  g2v.Bm[0] = Vd; g2v.Bm[1] = Vd; g2v.Bm[2] = Vd;
  g2v.C[0] = Vtg; g2v.C[1] = Vtg; g2v.C[2] = Vtg;
  g2v.alpha[0] = 1.f; g2v.alpha[1] = 1.f; g2v.alpha[2] = 1.f;
  gemm_bt<false><<<dim3(d / 128, BT / 128, 1), dim3(256), 0, stream>>>(
      g2v, nullptr, nullptr, d, BT, r);

  // flash attention
  mla_attn<<<dim3(1024), dim3(256), 0, stream>>>(Qu, Ku, Vtg, ctx);

  // output projection: out = ctx @ out_w^T + out_b (fp32 out)
  GemmB3 g3;
  g3.A[0] = ctx; g3.A[1] = ctx; g3.A[2] = ctx;
  g3.Bm[0] = wow; g3.Bm[1] = wow; g3.Bm[2] = wow;
  g3.C[0] = nullptr; g3.C[1] = nullptr; g3.C[2] = nullptr;
  g3.alpha[0] = 1.f; g3.alpha[1] = 1.f; g3.alpha[2] = 1.f;
  gemm_bt<true><<<dim3(BT / 128, d / 128, 1), dim3(256), 0, stream>>>(
      g3, (float*)d_out, ob, BT, d, d);
}

// Round 5
// 239.100 us; speedup vs baseline: 2.3646x; 1.0141x over previous
//
#include <hip/hip_runtime.h>
#include <stdint.h>

typedef __bf16 bf16x8 __attribute__((ext_vector_type(8)));
typedef float  f32x4  __attribute__((ext_vector_type(4)));
typedef float  f32x16 __attribute__((ext_vector_type(16)));
typedef unsigned short u16;
typedef unsigned int u32;
typedef u16 u16x8 __attribute__((ext_vector_type(8)));
typedef u32 u32x4 __attribute__((ext_vector_type(4)));

__device__ __forceinline__ u16 f2bf(float f) {
  uint32_t u = __builtin_bit_cast(uint32_t, f);
  u += 0x7fffu + ((u >> 16) & 1u);
  return (u16)(u >> 16);
}
__device__ __forceinline__ u32 pack2(float lo, float hi) {
  return (u32)f2bf(lo) | ((u32)f2bf(hi) << 16);
}

// async global->LDS, 16B per lane; lds base is wave-uniform (lane writes at +lane*16B)
__device__ __forceinline__ void async_cp16(const void* src, void* lds) {
  __builtin_amdgcn_global_load_lds(
      (const __attribute__((address_space(1))) uint32_t*)src,
      (__attribute__((address_space(3))) uint32_t*)lds, 16, 0, 0);
}

// ---------------- fused fp32 -> bf16 converts ----------------
struct CvtArgs {
  const float* in[8];
  u16* out[8];
  int n8[8];
  int nblk[8];
};
__global__ void cvt_multi(CvtArgs a) {
  int bx = blockIdx.x;
  int t = 0;
  while (t < 7 && bx >= a.nblk[t]) { bx -= a.nblk[t]; ++t; }
  const int i = bx * 256 + threadIdx.x;
  if (i >= a.n8[t]) return;
  const float4* p = (const float4*)a.in[t] + (size_t)i * 2;
  float4 va = p[0], vb = p[1];
  u16x8 r;
  r[0] = f2bf(va.x); r[1] = f2bf(va.y); r[2] = f2bf(va.z); r[3] = f2bf(va.w);
  r[4] = f2bf(vb.x); r[5] = f2bf(vb.y); r[6] = f2bf(vb.z); r[7] = f2bf(vb.w);
  ((u16x8*)a.out[t])[i] = r;
}

// ---------------- batched GEMM: C = A[M,K] * Bw[N,K]^T (unchanged) ----------
struct GemmB3 {
  const u16* A[3];
  const u16* Bm[3];
  u16* C[3];
  float alpha[3];
};

template<bool F32OUT>
__global__ __launch_bounds__(256, 2)
void gemm_bt(GemmB3 args, float* __restrict__ Cf, const float* __restrict__ bias,
             int M, int N, int K)
{
  __shared__ u16 At[128 * 32];
  __shared__ u16 Bt[128 * 32];
  const int z = blockIdx.z;
  const u16* __restrict__ A  = args.A[z];
  const u16* __restrict__ Bw = args.Bm[z];
  const int bm = blockIdx.x * 128;
  const int bn = blockIdx.y * 128;
  const int tid = threadIdx.x;
  const int w  = tid >> 6;
  const int l  = tid & 63;
  const int lr = l & 15;
  const int lg = l >> 4;
  const int wr = (w >> 1) * 64;
  const int wc = (w & 1) * 64;

  f32x4 acc[4][4];
  #pragma unroll
  for (int m = 0; m < 4; ++m)
    #pragma unroll
    for (int n = 0; n < 4; ++n) acc[m][n] = (f32x4){0.f, 0.f, 0.f, 0.f};

  for (int k0 = 0; k0 < K; k0 += 32) {
    __syncthreads();
    #pragma unroll
    for (int i = 0; i < 2; ++i) {
      const int gidx = i * 256 + tid;
      const int row  = gidx >> 2;
      const int g    = gidx & 3;
      const int gs   = (g - (row >> 1)) & 3;
      async_cp16(A  + (size_t)(bm + row) * K + k0 + gs * 8,
                 At + (size_t)(i * 256 + w * 64) * 8);
      async_cp16(Bw + (size_t)(bn + row) * K + k0 + gs * 8,
                 Bt + (size_t)(i * 256 + w * 64) * 8);
    }
    __syncthreads();
    bf16x8 af[4], bfr[4];
    #pragma unroll
    for (int m = 0; m < 4; ++m) {
      const int row = wr + m * 16 + lr;
      const int pos = (lg + (row >> 1)) & 3;
      af[m] = *(const bf16x8*)(At + row * 32 + pos * 8);
    }
    #pragma unroll
    for (int n = 0; n < 4; ++n) {
      const int row = wc + n * 16 + lr;
      const int pos = (lg + (row >> 1)) & 3;
      bfr[n] = *(const bf16x8*)(Bt + row * 32 + pos * 8);
    }
    #pragma unroll
    for (int m = 0; m < 4; ++m)
      #pragma unroll
      for (int n = 0; n < 4; ++n)
        acc[m][n] = __builtin_amdgcn_mfma_f32_16x16x32_bf16(af[m], bfr[n], acc[m][n], 0, 0, 0);
  }

  if constexpr (F32OUT) {
    #pragma unroll
    for (int n = 0; n < 4; ++n) {
      const int col = bn + wc + n * 16 + lr;
      const float bv = bias[col];
      #pragma unroll
      for (int m = 0; m < 4; ++m) {
        const int rbase = bm + wr + m * 16 + lg * 4;
        #pragma unroll
        for (int j = 0; j < 4; ++j)
          Cf[(size_t)(rbase + j) * N + col] = acc[m][n][j] + bv;
      }
    }
  } else {
    u16* __restrict__ C = args.C[z];
    const float alpha = args.alpha[z];
    #pragma unroll
    for (int n = 0; n < 4; ++n) {
      const int col = bn + wc + n * 16 + lr;
      #pragma unroll
      for (int m = 0; m < 4; ++m) {
        const int rbase = bm + wr + m * 16 + lg * 4;
        #pragma unroll
        for (int j = 0; j < 4; ++j)
          C[(size_t)(rbase + j) * N + col] = f2bf(acc[m][n][j] * alpha);
      }
    }
  }
}

// ---------------- flash attention, swapped 32x32 structure ------------------
// QBLK=128 (4 waves x 32 q rows), SBLK=64, dbuf staging. Lane owns one q row:
// QK = mfma_32x32x16(A=K, B=Q) -> score[s=(reg&3)+8*(reg>>2)+4*hi][q=ql];
// softmax in-lane + shfl_xor(32) partner folds; P packed to bf16 B-frags
// in-register (pair-pack + shfl_xor + hi-select); PV = mfma(A=V^T, B=P^T).
__global__ __launch_bounds__(256, 2)
void mla_attn(const u16* __restrict__ Qu, const u16* __restrict__ Ku,
              const u16* __restrict__ Vtg, u16* __restrict__ ctx)
{
  __shared__ u16 Ktb[2][64 * 128];   // [s][dh granules], pos g holds granule g^(s&15)
  __shared__ u16 Vtb[2][128 * 64];   // [dh][s granules], pos g holds granule g^(dh&7)

  const int bid = blockIdx.x;
  const int kk  = bid >> 5;
  const int qt  = (kk & 1) ? (kk >> 1) : (15 - (kk >> 1));  // heavy/light interleave
  const int bh  = bid & 31;
  const int b = bh >> 4, h = bh & 15;
  const int qbase = qt * 128;
  const int tid = threadIdx.x;
  const int w = tid >> 6, l = tid & 63;
  const int ql = l & 31;          // lane's q within wave tile (also D column)
  const int hi = l >> 5;
  const bool hb = (hi != 0);
  const int T = 2048;
  const size_t rs = 2048;

  const u16* Qp = Qu + ((size_t)b * T) * rs + (size_t)h * 128;
  const u16* Kp = Ku + ((size_t)b * T) * rs + (size_t)h * 128;
  const u16* Vp = Vtg + (size_t)(h * 128) * 4096 + (size_t)b * T;  // + dh*4096 + s

  const int qw = qbase + w * 32;  // wave's first q row
  const int qg = qw + ql;         // lane's global q row

  // Q B-frags: qf[kb] = Q[qg][kb*16 + hi*8 .. +7]
  bf16x8 qf[8];
  #pragma unroll
  for (int kb = 0; kb < 8; ++kb)
    qf[kb] = *(const bf16x8*)(Qp + (size_t)qg * rs + kb * 16 + hi * 8);

  f32x16 acc[4];
  #pragma unroll
  for (int dt = 0; dt < 4; ++dt)
    #pragma unroll
    for (int r = 0; r < 16; ++r) acc[dt][r] = 0.f;
  float mrun = -1.0e30f, lsum = 0.f;   // finite init: all exp2 args stay non-NaN

  // per-lane staging base pointers (swizzle baked in)
  const int ksr = tid >> 4;                       // K: s row 0..15 (+16 per i)
  const u16* kb0 = Kp + (size_t)ksr * rs + (((tid & 15) ^ (ksr & 15)) * 8);
  const int vsr = tid >> 3;                       // V: dh row 0..31 (+32 per i)
  const u16* vb0 = Vp + (size_t)vsr * 4096 + (((tid & 7) ^ (vsr & 7)) * 8);

  const int nT = 2 * qt + 2;

  auto stage = [&](int buf, int it) {
    const int s0 = it * 64;
    #pragma unroll
    for (int i = 0; i < 4; ++i)
      async_cp16(kb0 + (size_t)(s0 + i * 16) * rs, &Ktb[buf][(i * 256 + w * 64) * 8]);
    #pragma unroll
    for (int i = 0; i < 4; ++i)
      async_cp16(vb0 + (size_t)(i * 32) * 4096 + s0, &Vtb[buf][(i * 256 + w * 64) * 8]);
  };

  stage(0, 0);
  int cur = 0;

  for (int it = 0; it < nT; ++it) {
    __syncthreads();                      // drains prefetch of tile `it`
    if (it + 1 < nT) stage(cur ^ 1, it + 1);
    const int s0 = it * 64;
    if (s0 <= qw + 31) {                  // skip fully-masked wave-iters
      const u16* Kt = Ktb[cur];
      const u16* Vt = Vtb[cur];
      const bool diag = (it == (qw >> 6));
      #pragma unroll
      for (int st = 0; st < 2; ++st) {
        // --- QK^T over this 32-s subtile ---
        f32x16 c;
        #pragma unroll
        for (int r = 0; r < 16; ++r) c[r] = 0.f;
        __builtin_amdgcn_s_setprio(1);
        #pragma unroll
        for (int kb = 0; kb < 8; ++kb) {
          bf16x8 kf = *(const bf16x8*)(Kt + (st * 32 + ql) * 128 +
                                       (((2 * kb + hi) ^ (ql & 15)) * 8));
          c = __builtin_amdgcn_mfma_f32_32x32x16_bf16(kf, qf[kb], c, 0, 0, 0);
        }
        __builtin_amdgcn_s_setprio(0);

        // --- softmax (lane-local; s' = st*32 + 4*hi + (r&3) + 8*(r>>2)) ---
        float p[16];
        if (diag) {
          #pragma unroll
          for (int r = 0; r < 16; ++r) {
            const int sgl = s0 + st * 32 + 4 * hi + (r & 3) + 8 * (r >> 2);
            p[r] = (sgl <= qg) ? c[r] : -INFINITY;
          }
        } else {
          #pragma unroll
          for (int r = 0; r < 16; ++r) p[r] = c[r];
        }
        float mx = p[0];
        #pragma unroll
        for (int r = 1; r < 16; ++r) mx = fmaxf(mx, p[r]);
        mx = fmaxf(mx, __shfl_xor(mx, 32));   // fold hi partner (same q row)
        if (__any(mx > mrun + 8.f)) {         // defer-max rescale (log2 units)
          const float mnew = fmaxf(mrun, mx);
          const float scl = exp2f(mrun - mnew);   // finite - finite
          mrun = mnew;
          lsum *= scl;
          #pragma unroll
          for (int dt = 0; dt < 4; ++dt)
            #pragma unroll
            for (int r = 0; r < 16; ++r) acc[dt][r] *= scl;
        }
        float psum = 0.f;
        #pragma unroll
        for (int r = 0; r < 16; ++r) { p[r] = exp2f(p[r] - mrun); psum += p[r]; }
        lsum += psum + __shfl_xor(psum, 32);

        // --- pack P to bf16 B-frags (pair-pack + shfl_xor + hi-select) ---
        // own pairs Pk = (p[2k], p[2k+1]); Xk = partner lane's Pk.
        // B-frag needs lane(hi) to hold s' = st*32 + hi*8+e (f0) / 16+hi*8+e (f1):
        //   f0 = hi==0 ? {P0,P1,X0,X1} : {X2,X3,P2,P3}
        //   f1 = hi==0 ? {P4,P5,X4,X5} : {X6,X7,P6,P7}
        u32 P0 = pack2(p[0], p[1]),   P1 = pack2(p[2], p[3]);
        u32 P2 = pack2(p[4], p[5]),   P3 = pack2(p[6], p[7]);
        u32 P4 = pack2(p[8], p[9]),   P5 = pack2(p[10], p[11]);
        u32 P6 = pack2(p[12], p[13]), P7 = pack2(p[14], p[15]);
        u32 X0 = __shfl_xor(P0, 32), X1 = __shfl_xor(P1, 32);
        u32 X2 = __shfl_xor(P2, 32), X3 = __shfl_xor(P3, 32);
        u32 X4 = __shfl_xor(P4, 32), X5 = __shfl_xor(P5, 32);
        u32 X6 = __shfl_xor(P6, 32), X7 = __shfl_xor(P7, 32);
        const bf16x8 f0 = __builtin_bit_cast(bf16x8,
            (u32x4){hb ? X2 : P0, hb ? X3 : P1, hb ? P2 : X0, hb ? P3 : X1});
        const bf16x8 f1 = __builtin_bit_cast(bf16x8,
            (u32x4){hb ? X6 : P4, hb ? X7 : P5, hb ? P6 : X4, hb ? P7 : X5});

        // --- PV for ksteps 2*st, 2*st+1 ---
        __builtin_amdgcn_s_setprio(1);
        #pragma unroll
        for (int dt = 0; dt < 4; ++dt) {
          const int vrow = (dt * 32 + ql) * 64;
          bf16x8 v0 = *(const bf16x8*)(Vt + vrow + (((2 * (2 * st)     + hi) ^ (ql & 7)) * 8));
          bf16x8 v1 = *(const bf16x8*)(Vt + vrow + (((2 * (2 * st + 1) + hi) ^ (ql & 7)) * 8));
          acc[dt] = __builtin_amdgcn_mfma_f32_32x32x16_bf16(v0, f0, acc[dt], 0, 0, 0);
          acc[dt] = __builtin_amdgcn_mfma_f32_32x32x16_bf16(v1, f1, acc[dt], 0, 0, 0);
        }
        __builtin_amdgcn_s_setprio(0);
      }
    }
    cur ^= 1;
  }

  // epilogue: normalize (per-lane scalar), LDS round-trip, coalesced store
  __syncthreads();
  u16* Ot = &Ktb[0][0];   // 128 x 128 u16 = 32KB (spans both K buffers)
  const float inv = 1.f / lsum;
  const int orow = w * 32 + ql;
  #pragma unroll
  for (int dt = 0; dt < 4; ++dt) {
    #pragma unroll
    for (int rq = 0; rq < 4; ++rq) {
      const int dhb = dt * 32 + 8 * rq + 4 * hi;
      const int dhs = dhb ^ ((ql & 15) << 3);
      u16 e0 = f2bf(acc[dt][rq * 4 + 0] * inv);
      u16 e1 = f2bf(acc[dt][rq * 4 + 1] * inv);
      u16 e2 = f2bf(acc[dt][rq * 4 + 2] * inv);
      u16 e3 = f2bf(acc[dt][rq * 4 + 3] * inv);
      u32 w0 = (u32)e0 | ((u32)e1 << 16);
      u32 w1 = (u32)e2 | ((u32)e3 << 16);
      *(u32*)(Ot + orow * 128 + dhs)     = w0;
      *(u32*)(Ot + orow * 128 + dhs + 2) = w1;
    }
  }
  __syncthreads();
  #pragma unroll
  for (int i = 0; i < 8; ++i) {
    const int n = i * 256 + tid;
    const int q = n >> 4, g = n & 15;
    bf16x8 v = *(const bf16x8*)(Ot + q * 128 + ((g ^ (q & 15)) * 8));
    *(bf16x8*)(ctx + ((size_t)b * T + qbase + q) * rs + h * 128 + g * 8) = v;
  }
}

// ---------------- launcher ----------------
extern "C" void kernel_launch(void* const* d_in, const int* in_sizes, int n_in,
                              void* d_out, int out_size, void* d_ws, size_t ws_size,
                              hipStream_t stream)
{
  (void)n_in; (void)out_size; (void)ws_size;
  const float* x   = (const float*)d_in[0];
  const float* qdw = (const float*)d_in[1];
  const float* kdw = (const float*)d_in[2];
  const float* vdw = (const float*)d_in[3];
  const float* quw = (const float*)d_in[4];
  const float* kuw = (const float*)d_in[5];
  const float* vuw = (const float*)d_in[6];
  const float* oww = (const float*)d_in[7];
  const float* ob  = (const float*)d_in[8];

  const int d = 2048, r = 512;
  const int BT = in_sizes[0] / d;   // B*T = 4096

  u16* p = (u16*)d_ws;
  auto take = [&](size_t n) { u16* q = p; p += n; return q; };
  u16* xb  = take((size_t)BT * d);
  u16* wqd = take((size_t)r * d);
  u16* wkd = take((size_t)r * d);
  u16* wvd = take((size_t)r * d);
  u16* wqu = take((size_t)d * r);
  u16* wku = take((size_t)d * r);
  u16* wvu = take((size_t)d * r);
  u16* wow = take((size_t)d * d);
  u16* Qd  = take((size_t)BT * r);
  u16* Kd  = take((size_t)BT * r);
  u16* Vd  = take((size_t)BT * r);
  u16* Qu  = take((size_t)BT * d);
  u16* Ku  = take((size_t)BT * d);
  u16* Vtg = take((size_t)BT * d);   // transposed: [d][BT]
  u16* ctx = take((size_t)BT * d);

  CvtArgs ca;
  const float* ins[8] = {x, oww, qdw, kdw, vdw, quw, kuw, vuw};
  u16* outs[8]        = {xb, wow, wqd, wkd, wvd, wqu, wku, wvu};
  const size_t ns[8]  = {(size_t)BT * d, (size_t)d * d,
                         (size_t)r * d, (size_t)r * d, (size_t)r * d,
                         (size_t)d * r, (size_t)d * r, (size_t)d * r};
  int total_blk = 0;
  for (int t = 0; t < 8; ++t) {
    ca.in[t] = ins[t]; ca.out[t] = outs[t];
    ca.n8[t] = (int)(ns[t] / 8);
    ca.nblk[t] = (ca.n8[t] + 255) / 256;
    total_blk += ca.nblk[t];
  }
  cvt_multi<<<dim3(total_blk), dim3(256), 0, stream>>>(ca);

  // down projections: Qd/Kd/Vd = x @ Wd^T   [BT,2048] -> [BT,512]
  GemmB3 g1;
  g1.A[0] = xb;  g1.A[1] = xb;  g1.A[2] = xb;
  g1.Bm[0] = wqd; g1.Bm[1] = wkd; g1.Bm[2] = wvd;
  g1.C[0] = Qd;  g1.C[1] = Kd;  g1.C[2] = Vd;
  g1.alpha[0] = 1.f; g1.alpha[1] = 1.f; g1.alpha[2] = 1.f;
  gemm_bt<false><<<dim3(BT / 128, r / 128, 3), dim3(256), 0, stream>>>(
      g1, nullptr, nullptr, BT, r, d);

  // Q/K up projections; log2(e)/sqrt(128) folded into Qu (exp2-domain softmax)
  GemmB3 g2;
  g2.A[0] = Qd;  g2.A[1] = Kd;  g2.A[2] = Kd;
  g2.Bm[0] = wqu; g2.Bm[1] = wku; g2.Bm[2] = wku;
  g2.C[0] = Qu;  g2.C[1] = Ku;  g2.C[2] = Ku;
  g2.alpha[0] = 0.12751743f; g2.alpha[1] = 1.f; g2.alpha[2] = 1.f;
  gemm_bt<false><<<dim3(BT / 128, d / 128, 2), dim3(256), 0, stream>>>(
      g2, nullptr, nullptr, BT, d, r);

  // V up projection, TRANSPOSED output: Vtg[dh][bt] = vuw[dh,:] . Vd[bt,:]
  GemmB3 g2v;
  g2v.A[0] = wvu; g2v.A[1] = wvu; g2v.A[2] = wvu;
  g2v.Bm[0] = Vd; g2v.Bm[1] = Vd; g2v.Bm[2] = Vd;
  g2v.C[0] = Vtg; g2v.C[1] = Vtg; g2v.C[2] = Vtg;
  g2v.alpha[0] = 1.f; g2v.alpha[1] = 1.f; g2v.alpha[2] = 1.f;
  gemm_bt<false><<<dim3(d / 128, BT / 128, 1), dim3(256), 0, stream>>>(
      g2v, nullptr, nullptr, d, BT, r);

  // flash attention: 16 q-tiles x 32 (b,h)
  mla_attn<<<dim3(512), dim3(256), 0, stream>>>(Qu, Ku, Vtg, ctx);

  // output projection: out = ctx @ out_w^T + out_b (fp32 out)
  GemmB3 g3;
  g3.A[0] = ctx; g3.A[1] = ctx; g3.A[2] = ctx;
  g3.Bm[0] = wow; g3.Bm[1] = wow; g3.Bm[2] = wow;
  g3.C[0] = nullptr; g3.C[1] = nullptr; g3.C[2] = nullptr;
  g3.alpha[0] = 1.f; g3.alpha[1] = 1.f; g3.alpha[2] = 1.f;
  gemm_bt<true><<<dim3(BT / 128, d / 128, 1), dim3(256), 0, stream>>>(
      g3, (float*)d_out, ob, BT, d, d);
}

// Round 6
// 224.706 us; speedup vs baseline: 2.5161x; 1.0641x over previous
//
#include <hip/hip_runtime.h>
#include <stdint.h>

typedef __bf16 bf16x8 __attribute__((ext_vector_type(8)));
typedef float  f32x4  __attribute__((ext_vector_type(4)));
typedef float  f32x16 __attribute__((ext_vector_type(16)));
typedef unsigned short u16;
typedef unsigned int u32;
typedef u16 u16x8 __attribute__((ext_vector_type(8)));
typedef u32 u32x4 __attribute__((ext_vector_type(4)));

__device__ __forceinline__ u16 f2bf(float f) {
  uint32_t u = __builtin_bit_cast(uint32_t, f);
  u += 0x7fffu + ((u >> 16) & 1u);
  return (u16)(u >> 16);
}
__device__ __forceinline__ u32 cvtpk(float lo, float hi) {
  u32 r;
  asm("v_cvt_pk_bf16_f32 %0, %1, %2" : "=v"(r) : "v"(lo), "v"(hi));
  return r;
}

// async global->LDS, 16B per lane; lds base is wave-uniform (lane writes at +lane*16B)
__device__ __forceinline__ void async_cp16(const void* src, void* lds) {
  __builtin_amdgcn_global_load_lds(
      (const __attribute__((address_space(1))) uint32_t*)src,
      (__attribute__((address_space(3))) uint32_t*)lds, 16, 0, 0);
}

// ---------------- fused fp32 -> bf16 converts ----------------
struct CvtArgs {
  const float* in[8];
  u16* out[8];
  int n8[8];
  int nblk[8];
};
__global__ void cvt_multi(CvtArgs a) {
  int bx = blockIdx.x;
  int t = 0;
  while (t < 7 && bx >= a.nblk[t]) { bx -= a.nblk[t]; ++t; }
  const int i = bx * 256 + threadIdx.x;
  if (i >= a.n8[t]) return;
  const float4* p = (const float4*)a.in[t] + (size_t)i * 2;
  float4 va = p[0], vb = p[1];
  u16x8 r;
  r[0] = f2bf(va.x); r[1] = f2bf(va.y); r[2] = f2bf(va.z); r[3] = f2bf(va.w);
  r[4] = f2bf(vb.x); r[5] = f2bf(vb.y); r[6] = f2bf(vb.z); r[7] = f2bf(vb.w);
  ((u16x8*)a.out[t])[i] = r;
}

// ---------------- batched GEMM: C = A[M,K] * Bw[N,K]^T, BK=64 ----------------
// 128x128 tile, 4 waves (2x2), wave tile 64x64 = 4x4 frags of 16x16x32.
// LDS [128 rows][8 granules of 16B]; stored pos p holds source granule p^(row&7).
struct GemmB3 {
  const u16* A[3];
  const u16* Bm[3];
  u16* C[3];
  float alpha[3];
};

template<bool F32OUT>
__global__ __launch_bounds__(256, 2)
void gemm_bt(GemmB3 args, float* __restrict__ Cf, const float* __restrict__ bias,
             int M, int N, int K)
{
  __shared__ u16 At[128 * 64];
  __shared__ u16 Bt[128 * 64];
  const int z = blockIdx.z;
  const u16* __restrict__ A  = args.A[z];
  const u16* __restrict__ Bw = args.Bm[z];
  const int bm = blockIdx.x * 128;
  const int bn = blockIdx.y * 128;
  const int tid = threadIdx.x;
  const int w  = tid >> 6;
  const int l  = tid & 63;
  const int lr = l & 15;
  const int lg = l >> 4;
  const int wr = (w >> 1) * 64;
  const int wc = (w & 1) * 64;

  f32x4 acc[4][4];
  #pragma unroll
  for (int m = 0; m < 4; ++m)
    #pragma unroll
    for (int n = 0; n < 4; ++n) acc[m][n] = (f32x4){0.f, 0.f, 0.f, 0.f};

  for (int k0 = 0; k0 < K; k0 += 64) {
    __syncthreads();
    #pragma unroll
    for (int i = 0; i < 4; ++i) {
      const int slot = i * 256 + tid;
      const int row  = slot >> 3;      // 0..127
      const int pos  = slot & 7;
      const int gs   = pos ^ (row & 7);
      async_cp16(A  + (size_t)(bm + row) * K + k0 + gs * 8,
                 At + (size_t)(i * 256 + w * 64) * 8);
      async_cp16(Bw + (size_t)(bn + row) * K + k0 + gs * 8,
                 Bt + (size_t)(i * 256 + w * 64) * 8);
    }
    __syncthreads();
    #pragma unroll
    for (int kk = 0; kk < 2; ++kk) {
      bf16x8 af[4], bfr[4];
      #pragma unroll
      for (int m = 0; m < 4; ++m) {
        const int row = wr + m * 16 + lr;
        const int pos = (kk * 4 + lg) ^ (row & 7);
        af[m] = *(const bf16x8*)(At + row * 64 + pos * 8);
      }
      #pragma unroll
      for (int n = 0; n < 4; ++n) {
        const int row = wc + n * 16 + lr;
        const int pos = (kk * 4 + lg) ^ (row & 7);
        bfr[n] = *(const bf16x8*)(Bt + row * 64 + pos * 8);
      }
      #pragma unroll
      for (int m = 0; m < 4; ++m)
        #pragma unroll
        for (int n = 0; n < 4; ++n)
          acc[m][n] = __builtin_amdgcn_mfma_f32_16x16x32_bf16(af[m], bfr[n], acc[m][n], 0, 0, 0);
    }
  }

  if constexpr (F32OUT) {
    #pragma unroll
    for (int n = 0; n < 4; ++n) {
      const int col = bn + wc + n * 16 + lr;
      const float bv = bias[col];
      #pragma unroll
      for (int m = 0; m < 4; ++m) {
        const int rbase = bm + wr + m * 16 + lg * 4;
        #pragma unroll
        for (int j = 0; j < 4; ++j)
          Cf[(size_t)(rbase + j) * N + col] = acc[m][n][j] + bv;
      }
    }
  } else {
    u16* __restrict__ C = args.C[z];
    const float alpha = args.alpha[z];
    #pragma unroll
    for (int n = 0; n < 4; ++n) {
      const int col = bn + wc + n * 16 + lr;
      #pragma unroll
      for (int m = 0; m < 4; ++m) {
        const int rbase = bm + wr + m * 16 + lg * 4;
        #pragma unroll
        for (int j = 0; j < 4; ++j)
          C[(size_t)(rbase + j) * N + col] = f2bf(acc[m][n][j] * alpha);
      }
    }
  }
}

// ---------------- flash attention, swapped 32x32, fused-subtile softmax ------
// QBLK=128 (4 waves x 32 q rows), SBLK=64, dbuf staging. Lane owns one q row.
// Per 64-s iter: 16 QK MFMA -> ONE combined 32-wide softmax (1 shfl fold,
// 1 rescale check) -> cvt_pk + 8-shfl pack into 4 B-frags -> 16 PV MFMA.
__global__ __launch_bounds__(256, 2)
void mla_attn(const u16* __restrict__ Qu, const u16* __restrict__ Ku,
              const u16* __restrict__ Vtg, u16* __restrict__ ctx)
{
  __shared__ u16 Ktb[2][64 * 128];   // [s][dh granules], pos g holds granule g^(s&15)
  __shared__ u16 Vtb[2][128 * 64];   // [dh][s granules], pos g holds granule g^(dh&7)

  const int bid = blockIdx.x;
  const int kk  = bid >> 5;
  const int qt  = (kk & 1) ? (kk >> 1) : (15 - (kk >> 1));  // heavy/light interleave
  const int bh  = bid & 31;
  const int b = bh >> 4, h = bh & 15;
  const int qbase = qt * 128;
  const int tid = threadIdx.x;
  const int w = tid >> 6, l = tid & 63;
  const int ql = l & 31;          // lane's q within wave tile (also D column)
  const int hi = l >> 5;
  const bool hb = (hi != 0);
  const int T = 2048;
  const size_t rs = 2048;

  const u16* Qp = Qu + ((size_t)b * T) * rs + (size_t)h * 128;
  const u16* Kp = Ku + ((size_t)b * T) * rs + (size_t)h * 128;
  const u16* Vp = Vtg + (size_t)(h * 128) * 4096 + (size_t)b * T;  // + dh*4096 + s

  const int qw = qbase + w * 32;  // wave's first q row
  const int qg = qw + ql;         // lane's global q row

  bf16x8 qf[8];
  #pragma unroll
  for (int kb = 0; kb < 8; ++kb)
    qf[kb] = *(const bf16x8*)(Qp + (size_t)qg * rs + kb * 16 + hi * 8);

  f32x16 acc[4];
  #pragma unroll
  for (int dt = 0; dt < 4; ++dt)
    #pragma unroll
    for (int r = 0; r < 16; ++r) acc[dt][r] = 0.f;
  float mrun = -1.0e30f, lsum = 0.f;   // finite init: all exp2 args stay non-NaN

  const int ksr = tid >> 4;
  const u16* kb0 = Kp + (size_t)ksr * rs + (((tid & 15) ^ (ksr & 15)) * 8);
  const int vsr = tid >> 3;
  const u16* vb0 = Vp + (size_t)vsr * 4096 + (((tid & 7) ^ (vsr & 7)) * 8);

  const int nT = 2 * qt + 2;

  auto stage = [&](int buf, int it) {
    const int s0 = it * 64;
    #pragma unroll
    for (int i = 0; i < 4; ++i)
      async_cp16(kb0 + (size_t)(s0 + i * 16) * rs, &Ktb[buf][(i * 256 + w * 64) * 8]);
    #pragma unroll
    for (int i = 0; i < 4; ++i)
      async_cp16(vb0 + (size_t)(i * 32) * 4096 + s0, &Vtb[buf][(i * 256 + w * 64) * 8]);
  };

  stage(0, 0);
  int cur = 0;

  for (int it = 0; it < nT; ++it) {
    __syncthreads();                      // drains prefetch of tile `it`
    if (it + 1 < nT) stage(cur ^ 1, it + 1);
    const int s0 = it * 64;
    if (s0 <= qw + 31) {                  // skip fully-masked wave-iters
      const u16* Kt = Ktb[cur];
      const u16* Vt = Vtb[cur];
      const bool diag = (it == (qw >> 6));

      // --- QK^T, both 32-s subtiles back to back ---
      f32x16 c0, c1;
      #pragma unroll
      for (int r = 0; r < 16; ++r) { c0[r] = 0.f; c1[r] = 0.f; }
      __builtin_amdgcn_s_setprio(1);
      #pragma unroll
      for (int kb = 0; kb < 8; ++kb) {
        bf16x8 kf0 = *(const bf16x8*)(Kt + ql * 128 + (((2 * kb + hi) ^ (ql & 15)) * 8));
        c0 = __builtin_amdgcn_mfma_f32_32x32x16_bf16(kf0, qf[kb], c0, 0, 0, 0);
      }
      #pragma unroll
      for (int kb = 0; kb < 8; ++kb) {
        bf16x8 kf1 = *(const bf16x8*)(Kt + (32 + ql) * 128 + (((2 * kb + hi) ^ (ql & 15)) * 8));
        c1 = __builtin_amdgcn_mfma_f32_32x32x16_bf16(kf1, qf[kb], c1, 0, 0, 0);
      }
      __builtin_amdgcn_s_setprio(0);

      // --- combined softmax over 32 scores ---
      // p[st*16+r] holds s = s0 + st*32 + 4*hi + (r&3) + 8*(r>>2)
      float p[32];
      if (diag) {
        #pragma unroll
        for (int r = 0; r < 16; ++r) {
          const int sg0 = s0 + 4 * hi + (r & 3) + 8 * (r >> 2);
          p[r]      = (sg0      <= qg) ? c0[r] : -INFINITY;
          p[16 + r] = (sg0 + 32 <= qg) ? c1[r] : -INFINITY;
        }
      } else {
        #pragma unroll
        for (int r = 0; r < 16; ++r) { p[r] = c0[r]; p[16 + r] = c1[r]; }
      }
      float mx = fmaxf(p[0], p[1]);
      #pragma unroll
      for (int r = 2; r < 32; ++r) mx = fmaxf(mx, p[r]);
      mx = fmaxf(mx, __shfl_xor(mx, 32));
      if (__any(mx > mrun + 8.f)) {       // defer-max rescale (log2 units)
        const float mnew = fmaxf(mrun, mx);
        const float scl = exp2f(mrun - mnew);
        mrun = mnew;
        lsum *= scl;
        #pragma unroll
        for (int dt = 0; dt < 4; ++dt)
          #pragma unroll
          for (int r = 0; r < 16; ++r) acc[dt][r] *= scl;
      }
      float psum = 0.f;
      #pragma unroll
      for (int r = 0; r < 32; ++r) { p[r] = exp2f(p[r] - mrun); psum += p[r]; }
      lsum += psum + __shfl_xor(psum, 32);

      // --- pack P to 4 bf16 B-frags (cvt_pk + bidirectional shfl + select) ---
      // per 16: Pk=(p[2k],p[2k+1]); Yi carry partner values both directions:
      //   f0 = hi?{X2,X3,P2,P3}:{P0,P1,X0,X1},  f1 = hi?{X6,X7,P6,P7}:{P4,P5,X4,X5}
      bf16x8 fr[4];
      #pragma unroll
      for (int st = 0; st < 2; ++st) {
        const int o = st * 16;
        u32 P0 = cvtpk(p[o + 0], p[o + 1]),   P1 = cvtpk(p[o + 2], p[o + 3]);
        u32 P2 = cvtpk(p[o + 4], p[o + 5]),   P3 = cvtpk(p[o + 6], p[o + 7]);
        u32 P4 = cvtpk(p[o + 8], p[o + 9]),   P5 = cvtpk(p[o + 10], p[o + 11]);
        u32 P6 = cvtpk(p[o + 12], p[o + 13]), P7 = cvtpk(p[o + 14], p[o + 15]);
        u32 Y0 = __shfl_xor(hb ? P0 : P2, 32);   // hi0 gets X0, hi1 gets X2
        u32 Y1 = __shfl_xor(hb ? P1 : P3, 32);
        u32 Y2 = __shfl_xor(hb ? P4 : P6, 32);
        u32 Y3 = __shfl_xor(hb ? P5 : P7, 32);
        fr[st * 2 + 0] = __builtin_bit_cast(bf16x8,
            (u32x4){hb ? Y0 : P0, hb ? Y1 : P1, hb ? P2 : Y0, hb ? P3 : Y1});
        fr[st * 2 + 1] = __builtin_bit_cast(bf16x8,
            (u32x4){hb ? Y2 : P4, hb ? Y3 : P5, hb ? P6 : Y2, hb ? P7 : Y3});
      }

      // --- PV: 4 ksteps of 16 s each ---
      __builtin_amdgcn_s_setprio(1);
      #pragma unroll
      for (int dt = 0; dt < 4; ++dt) {
        const int vrow = (dt * 32 + ql) * 64;
        #pragma unroll
        for (int ks = 0; ks < 4; ++ks) {
          bf16x8 v = *(const bf16x8*)(Vt + vrow + (((2 * ks + hi) ^ (ql & 7)) * 8));
          acc[dt] = __builtin_amdgcn_mfma_f32_32x32x16_bf16(v, fr[ks], acc[dt], 0, 0, 0);
        }
      }
      __builtin_amdgcn_s_setprio(0);
    }
    cur ^= 1;
  }

  // epilogue: normalize (per-lane scalar), LDS round-trip, coalesced store
  __syncthreads();
  u16* Ot = &Ktb[0][0];   // 128 x 128 u16 = 32KB (spans both K buffers)
  const float inv = 1.f / lsum;
  const int orow = w * 32 + ql;
  #pragma unroll
  for (int dt = 0; dt < 4; ++dt) {
    #pragma unroll
    for (int rq = 0; rq < 4; ++rq) {
      const int dhb = dt * 32 + 8 * rq + 4 * hi;
      const int dhs = dhb ^ ((ql & 15) << 3);
      u16 e0 = f2bf(acc[dt][rq * 4 + 0] * inv);
      u16 e1 = f2bf(acc[dt][rq * 4 + 1] * inv);
      u16 e2 = f2bf(acc[dt][rq * 4 + 2] * inv);
      u16 e3 = f2bf(acc[dt][rq * 4 + 3] * inv);
      u32 w0 = (u32)e0 | ((u32)e1 << 16);
      u32 w1 = (u32)e2 | ((u32)e3 << 16);
      *(u32*)(Ot + orow * 128 + dhs)     = w0;
      *(u32*)(Ot + orow * 128 + dhs + 2) = w1;
    }
  }
  __syncthreads();
  #pragma unroll
  for (int i = 0; i < 8; ++i) {
    const int n = i * 256 + tid;
    const int q = n >> 4, g = n & 15;
    bf16x8 v = *(const bf16x8*)(Ot + q * 128 + ((g ^ (q & 15)) * 8));
    *(bf16x8*)(ctx + ((size_t)b * T + qbase + q) * rs + h * 128 + g * 8) = v;
  }
}

// ---------------- launcher ----------------
extern "C" void kernel_launch(void* const* d_in, const int* in_sizes, int n_in,
                              void* d_out, int out_size, void* d_ws, size_t ws_size,
                              hipStream_t stream)
{
  (void)n_in; (void)out_size; (void)ws_size;
  const float* x   = (const float*)d_in[0];
  const float* qdw = (const float*)d_in[1];
  const float* kdw = (const float*)d_in[2];
  const float* vdw = (const float*)d_in[3];
  const float* quw = (const float*)d_in[4];
  const float* kuw = (const float*)d_in[5];
  const float* vuw = (const float*)d_in[6];
  const float* oww = (const float*)d_in[7];
  const float* ob  = (const float*)d_in[8];

  const int d = 2048, r = 512;
  const int BT = in_sizes[0] / d;   // B*T = 4096

  u16* p = (u16*)d_ws;
  auto take = [&](size_t n) { u16* q = p; p += n; return q; };
  u16* xb  = take((size_t)BT * d);
  u16* wqd = take((size_t)r * d);
  u16* wkd = take((size_t)r * d);
  u16* wvd = take((size_t)r * d);
  u16* wqu = take((size_t)d * r);
  u16* wku = take((size_t)d * r);
  u16* wvu = take((size_t)d * r);
  u16* wow = take((size_t)d * d);
  u16* Qd  = take((size_t)BT * r);
  u16* Kd  = take((size_t)BT * r);
  u16* Vd  = take((size_t)BT * r);
  u16* Qu  = take((size_t)BT * d);
  u16* Ku  = take((size_t)BT * d);
  u16* Vtg = take((size_t)BT * d);   // transposed: [d][BT]
  u16* ctx = take((size_t)BT * d);

  CvtArgs ca;
  const float* ins[8] = {x, oww, qdw, kdw, vdw, quw, kuw, vuw};
  u16* outs[8]        = {xb, wow, wqd, wkd, wvd, wqu, wku, wvu};
  const size_t ns[8]  = {(size_t)BT * d, (size_t)d * d,
                         (size_t)r * d, (size_t)r * d, (size_t)r * d,
                         (size_t)d * r, (size_t)d * r, (size_t)d * r};
  int total_blk = 0;
  for (int t = 0; t < 8; ++t) {
    ca.in[t] = ins[t]; ca.out[t] = outs[t];
    ca.n8[t] = (int)(ns[t] / 8);
    ca.nblk[t] = (ca.n8[t] + 255) / 256;
    total_blk += ca.nblk[t];
  }
  cvt_multi<<<dim3(total_blk), dim3(256), 0, stream>>>(ca);

  // down projections: Qd/Kd/Vd = x @ Wd^T   [BT,2048] -> [BT,512]
  GemmB3 g1;
  g1.A[0] = xb;  g1.A[1] = xb;  g1.A[2] = xb;
  g1.Bm[0] = wqd; g1.Bm[1] = wkd; g1.Bm[2] = wvd;
  g1.C[0] = Qd;  g1.C[1] = Kd;  g1.C[2] = Vd;
  g1.alpha[0] = 1.f; g1.alpha[1] = 1.f; g1.alpha[2] = 1.f;
  gemm_bt<false><<<dim3(BT / 128, r / 128, 3), dim3(256), 0, stream>>>(
      g1, nullptr, nullptr, BT, r, d);

  // Q/K up projections; log2(e)/sqrt(128) folded into Qu (exp2-domain softmax)
  GemmB3 g2;
  g2.A[0] = Qd;  g2.A[1] = Kd;  g2.A[2] = Kd;
  g2.Bm[0] = wqu; g2.Bm[1] = wku; g2.Bm[2] = wku;
  g2.C[0] = Qu;  g2.C[1] = Ku;  g2.C[2] = Ku;
  g2.alpha[0] = 0.12751743f; g2.alpha[1] = 1.f; g2.alpha[2] = 1.f;
  gemm_bt<false><<<dim3(BT / 128, d / 128, 2), dim3(256), 0, stream>>>(
      g2, nullptr, nullptr, BT, d, r);

  // V up projection, TRANSPOSED output: Vtg[dh][bt] = vuw[dh,:] . Vd[bt,:]
  GemmB3 g2v;
  g2v.A[0] = wvu; g2v.A[1] = wvu; g2v.A[2] = wvu;
  g2v.Bm[0] = Vd; g2v.Bm[1] = Vd; g2v.Bm[2] = Vd;
  g2v.C[0] = Vtg; g2v.C[1] = Vtg; g2v.C[2] = Vtg;
  g2v.alpha[0] = 1.f; g2v.alpha[1] = 1.f; g2v.alpha[2] = 1.f;
  gemm_bt<false><<<dim3(d / 128, BT / 128, 1), dim3(256), 0, stream>>>(
      g2v, nullptr, nullptr, d, BT, r);

  // flash attention: 16 q-tiles x 32 (b,h)
  mla_attn<<<dim3(512), dim3(256), 0, stream>>>(Qu, Ku, Vtg, ctx);

  // output projection: out = ctx @ out_w^T + out_b (fp32 out)
  GemmB3 g3;
  g3.A[0] = ctx; g3.A[1] = ctx; g3.A[2] = ctx;
  g3.Bm[0] = wow; g3.Bm[1] = wow; g3.Bm[2] = wow;
  g3.C[0] = nullptr; g3.C[1] = nullptr; g3.C[2] = nullptr;
  g3.alpha[0] = 1.f; g3.alpha[1] = 1.f; g3.alpha[2] = 1.f;
  gemm_bt<true><<<dim3(BT / 128, d / 128, 1), dim3(256), 0, stream>>>(
      g3, (float*)d_out, ob, BT, d, d);
}